// Round 25
// baseline (309.353 us; speedup 1.0000x reference)
//
#include <hip/hip_runtime.h>
#include <hip/hip_bf16.h>

typedef __attribute__((ext_vector_type(8))) short short8;
typedef __attribute__((ext_vector_type(4))) short short4v;
typedef __attribute__((ext_vector_type(4))) float floatx4;

__device__ __forceinline__ void gload_lds16(const void* g, void* l) {
  __builtin_amdgcn_global_load_lds(
      (const __attribute__((address_space(1))) void*)g,
      (__attribute__((address_space(3))) void*)l, 16, 0, 0);
}

// tanh-approx GELU via sigmoid; branch-free (v_exp + v_rcp)
__device__ __forceinline__ float gelu_fast(float x) {
  float z = 1.5957691216f * (x + 0.044715f * x * x * x);
  float e = __expf(-z);
  return x * __builtin_amdgcn_rcpf(1.0f + e);
}

#define FENCE() asm volatile("" ::: "memory")

// ==== 128x128x(K=512) NT GEMM core — A staged in LDS, B streamed from L2 ====
// 512 thr / 8 waves (2x4), per-wave out 64x32, LDS 32KB dbuf (A only)
// -> up to 4 blk/CU (32 waves/CU). B read per-fragment from global (L2-res
// 512KB weight; XCD-chunked swizzle keeps it hot). A-side: T2 swizzle,
// STAGE-before-compute, one vmcnt(0)+barrier per K-step.
// GELU-in-epilogue BANNED (R14: +32us pathology). Swizzle computed by caller.
template<bool HASBIAS, bool OUT_F32>
__device__ __forceinline__
void gemm128_core(const __hip_bfloat16* __restrict__ A,
                  const __hip_bfloat16* __restrict__ B,
                  const float* __restrict__ bias,
                  void* __restrict__ C,
                  int bx, int by)
{
  __shared__ __align__(16) __hip_bfloat16 SB[2][128 * 64];  // 32KB (A only)

  const int tid  = threadIdx.x;
  const int lane = tid & 63;
  const int wid  = tid >> 6;   // 0..7
  const int wr   = wid >> 2;   // 0..1 (row half: 64 rows)
  const int wc   = wid & 3;    // 0..3 (col quarter: 32 cols)
  const int brow = by * 128;
  const int bcol = bx * 128;

  floatx4 acc[4][2];
#pragma unroll
  for (int i = 0; i < 4; i++)
#pragma unroll
    for (int j = 0; j < 2; j++) acc[i][j] = (floatx4){0.f, 0.f, 0.f, 0.f};

  // A staging: 2 rounds x 64 rows; row = r*64 + (tid>>3); slot tid&7
  const int srow  = tid >> 3;                       // 0..63
  const int skoff = (((tid & 7) ^ (srow & 7))) * 8;

  auto STAGE = [&](int buf, int kt) {
    const int k0 = kt * 64;
#pragma unroll
    for (int r = 0; r < 2; ++r)
      gload_lds16(A + (size_t)(brow + r * 64 + srow) * 512 + k0 + skoff,
                  (void*)(&SB[buf][0] + r * 4096 + tid * 8));
  };

  const int rs0 = (((lane >> 4)) ^ (lane & 7)) * 8;
  const int rs1 = ((4 + (lane >> 4)) ^ (lane & 7)) * 8;

  // per-lane B base: row = bcol + wc*32 + (lane&15); k-offset (lane>>4)*8
  const __hip_bfloat16* Bp =
      B + (size_t)(bcol + wc * 32 + (lane & 15)) * 512 + (lane >> 4) * 8;

  STAGE(0, 0);
  asm volatile("s_waitcnt vmcnt(0)" ::: "memory");
  __builtin_amdgcn_s_barrier();
  FENCE();

  for (int kt = 0; kt < 8; ++kt) {
    const int cur = kt & 1;
    if (kt < 7) STAGE(cur ^ 1, kt + 1);   // next A tile flies under compute
    const __hip_bfloat16* As = &SB[cur][0];
    __builtin_amdgcn_s_setprio(1);
#pragma unroll
    for (int kk = 0; kk < 2; ++kk) {
      const int rs = kk ? rs1 : rs0;
      short8 a[4], b[2];
#pragma unroll
      for (int j = 0; j < 2; j++)
        b[j] = *(const short8*)(Bp + (size_t)(j * 16) * 512 + kt * 64 + kk * 32);
#pragma unroll
      for (int i = 0; i < 4; i++)
        a[i] = *(const short8*)(As + (wr * 64 + i * 16 + (lane & 15)) * 64 + rs);
#pragma unroll
      for (int i = 0; i < 4; i++)
#pragma unroll
        for (int j = 0; j < 2; j++)
          acc[i][j] = __builtin_amdgcn_mfma_f32_16x16x32_bf16(a[i], b[j], acc[i][j], 0, 0, 0);
    }
    __builtin_amdgcn_s_setprio(0);

    if (kt < 7) {
      asm volatile("s_waitcnt vmcnt(0)" ::: "memory");
      __builtin_amdgcn_s_barrier();
      FENCE();
    }
  }

  // epilogue: C/D layout col=lane&15, row=(lane>>4)*4+reg
#pragma unroll
  for (int i = 0; i < 4; i++) {
    const int row0 = brow + wr * 64 + i * 16 + (lane >> 4) * 4;
#pragma unroll
    for (int j = 0; j < 2; j++) {
      const int col = bcol + wc * 32 + j * 16 + (lane & 15);
      const float bv = HASBIAS ? bias[col] : 0.f;
#pragma unroll
      for (int r = 0; r < 4; r++) {
        float v = acc[i][j][r] + bv;
        if (OUT_F32)
          ((float*)C)[(size_t)(row0 + r) * 512 + col] = v;
        else
          ((__hip_bfloat16*)C)[(size_t)(row0 + r) * 512 + col] = __float2bfloat16(v);
      }
    }
  }
}

// chunked-XCD swizzle helper: flat id -> (bx, by, bz); total must be /8
__device__ __forceinline__ void swz_chunked(int gx, int gy, int total,
                                            int& bx, int& by, int& bz) {
  const int f = blockIdx.x + gx * (blockIdx.y + gy * blockIdx.z);
  const int l = (f & 7) * (total >> 3) + (f >> 3);
  bx = l % gx;
  const int rr = l / gx;
  by = rr % gy;
  bz = rr / gy;
}

// ---- named instantiations ----
__global__ __launch_bounds__(512, 4)
void g128_h12(const __hip_bfloat16* Xb,
              const __hip_bfloat16* W1a, const __hip_bfloat16* W2a,
              const float* b1a, const float* b2a,
              __hip_bfloat16* H1, __hip_bfloat16* H2) {
  int bx, by, bz;
  swz_chunked(4, 256, 2048, bx, by, bz);
  const __hip_bfloat16* B = bz ? W2a : W1a;
  const float* bias       = bz ? b2a : b1a;
  __hip_bfloat16* C       = bz ? H2 : H1;
  gemm128_core<true, false>(Xb, B, bias, C, bx, by);
}
__global__ __launch_bounds__(512, 4)
void g128_w12(const __hip_bfloat16* H1, const __hip_bfloat16* H2,
              const __hip_bfloat16* W1b, const __hip_bfloat16* W2b,
              const float* b1b, const float* b2b,
              __hip_bfloat16* W1n, __hip_bfloat16* W2m) {
  int bx, by, bz;
  swz_chunked(4, 256, 2048, bx, by, bz);
  const __hip_bfloat16* A = bz ? H2 : H1;
  const __hip_bfloat16* B = bz ? W2b : W1b;
  const float* bias       = bz ? b2b : b1b;
  __hip_bfloat16* C       = bz ? W2m : W1n;
  gemm128_core<true, false>(A, B, bias, C, bx, by);
}
__global__ __launch_bounds__(512, 4)
void g128_w1(const __hip_bfloat16* A, const __hip_bfloat16* B, const float* bias,
             __hip_bfloat16* C) {
  int bx, by, bz;
  swz_chunked(4, 256, 1024, bx, by, bz);
  gemm128_core<true, false>(A, B, bias, C, bx, by);
}
__global__ __launch_bounds__(512, 4)
void g128_w2(const __hip_bfloat16* A, const __hip_bfloat16* B, const float* bias,
             __hip_bfloat16* C) {
  int bx, by, bz;
  swz_chunked(4, 256, 1024, bx, by, bz);
  gemm128_core<true, false>(A, B, bias, C, bx, by);
}
__global__ __launch_bounds__(512, 4)
void g128_y(const __hip_bfloat16* A, const __hip_bfloat16* B, float* C) {
  int bx, by, bz;
  swz_chunked(4, 32, 1024, bx, by, bz);
  gemm128_core<false, true>(A + (size_t)bz * 4096 * 512,
                            B + (size_t)bz * 262144, nullptr,
                            C + (size_t)bz * 4096 * 512, bx, by);
}

// ====== P kernel: 2 kc-chunks accumulated per block (K=1024, 16 steps) ======
// grid (4,4,32) = 512 blocks; 512 thr / 8 waves; A in LDS, B streamed.
__global__ __launch_bounds__(512, 4)
void g128_p(const __hip_bfloat16* __restrict__ Ag,
            const __hip_bfloat16* __restrict__ Bg,
            __hip_bfloat16* __restrict__ Cg)
{
  const int f = blockIdx.x + 4 * (blockIdx.y + 4 * blockIdx.z);
  const int xcd = f & 7, s = f >> 3;     // s: 0..63
  const int zq = xcd + 8 * (s >> 4);     // 0..31
  const int t  = s & 15;
  const int by = t >> 2;
  const int bx = t & 3;

  const __hip_bfloat16* A = Ag + (size_t)zq * 2 * 262144;
  const __hip_bfloat16* B = Bg + (size_t)zq * 2 * 262144;
  __hip_bfloat16*       C = Cg + (size_t)zq * 262144;

  __shared__ __align__(16) __hip_bfloat16 SB[2][128 * 64];  // 32KB

  const int tid  = threadIdx.x;
  const int lane = tid & 63;
  const int wid  = tid >> 6;   // 0..7
  const int wr   = wid >> 2;   // 0..1
  const int wc   = wid & 3;    // 0..3
  const int brow = by * 128;
  const int bcol = bx * 128;

  floatx4 acc[4][2];
#pragma unroll
  for (int i = 0; i < 4; i++)
#pragma unroll
    for (int j = 0; j < 2; j++) acc[i][j] = (floatx4){0.f, 0.f, 0.f, 0.f};

  const int srow  = tid >> 3;
  const int skoff = (((tid & 7) ^ (srow & 7))) * 8;

  auto STAGE = [&](int buf, int kt) {
    const size_t cb = (size_t)(kt >> 3) * 262144;   // chunk base
    const int k0 = (kt & 7) * 64;
#pragma unroll
    for (int r = 0; r < 2; ++r)
      gload_lds16(A + cb + (size_t)(brow + r * 64 + srow) * 512 + k0 + skoff,
                  (void*)(&SB[buf][0] + r * 4096 + tid * 8));
  };

  const int rs0 = (((lane >> 4)) ^ (lane & 7)) * 8;
  const int rs1 = ((4 + (lane >> 4)) ^ (lane & 7)) * 8;

  const __hip_bfloat16* Bp =
      B + (size_t)(bcol + wc * 32 + (lane & 15)) * 512 + (lane >> 4) * 8;

  STAGE(0, 0);
  asm volatile("s_waitcnt vmcnt(0)" ::: "memory");
  __builtin_amdgcn_s_barrier();
  FENCE();

  for (int kt = 0; kt < 16; ++kt) {
    const int cur = kt & 1;
    if (kt < 15) STAGE(cur ^ 1, kt + 1);
    const __hip_bfloat16* As = &SB[cur][0];
    const size_t cb = (size_t)(kt >> 3) * 262144;
    const int k0 = (kt & 7) * 64;
    __builtin_amdgcn_s_setprio(1);
#pragma unroll
    for (int kk = 0; kk < 2; ++kk) {
      const int rs = kk ? rs1 : rs0;
      short8 a[4], b[2];
#pragma unroll
      for (int j = 0; j < 2; j++)
        b[j] = *(const short8*)(Bp + cb + (size_t)(j * 16) * 512 + k0 + kk * 32);
#pragma unroll
      for (int i = 0; i < 4; i++)
        a[i] = *(const short8*)(As + (wr * 64 + i * 16 + (lane & 15)) * 64 + rs);
#pragma unroll
      for (int i = 0; i < 4; i++)
#pragma unroll
        for (int j = 0; j < 2; j++)
          acc[i][j] = __builtin_amdgcn_mfma_f32_16x16x32_bf16(a[i], b[j], acc[i][j], 0, 0, 0);
    }
    __builtin_amdgcn_s_setprio(0);

    if (kt < 15) {
      asm volatile("s_waitcnt vmcnt(0)" ::: "memory");
      __builtin_amdgcn_s_barrier();
      FENCE();
    }
  }

#pragma unroll
  for (int i = 0; i < 4; i++) {
    const int row0 = brow + wr * 64 + i * 16 + (lane >> 4) * 4;
#pragma unroll
    for (int j = 0; j < 2; j++) {
      const int col = bcol + wc * 32 + j * 16 + (lane & 15);
#pragma unroll
      for (int r = 0; r < 4; r++)
        C[(size_t)(row0 + r) * 512 + col] = __float2bfloat16(acc[i][j][r]);
    }
  }
}

// in-place GELU over bf16 buffer, 8 elems/thread
__global__ __launch_bounds__(256)
void gelu_inplace(__hip_bfloat16* __restrict__ H, long n) {
  long i = ((long)blockIdx.x * 256 + threadIdx.x) * 8;
  if (i >= n) return;
  short8 v = *(const short8*)(H + i);
  short8 o;
#pragma unroll
  for (int j = 0; j < 8; j++) {
    float x = __bfloat162float(((const __hip_bfloat16*)&v)[j]);
    ((__hip_bfloat16*)&o)[j] = __float2bfloat16(gelu_fast(x));
  }
  *(short8*)(H + i) = o;
}

// fused fp32->bf16 for the four 512x512 weights (one launch)
__global__ __launch_bounds__(256)
void cvt_w4(const float* __restrict__ w0, const float* __restrict__ w1,
            const float* __restrict__ w2, const float* __restrict__ w3,
            __hip_bfloat16* __restrict__ o0, __hip_bfloat16* __restrict__ o1,
            __hip_bfloat16* __restrict__ o2, __hip_bfloat16* __restrict__ o3) {
  const int sel = blockIdx.x >> 7;           // 128 blocks per weight
  const float* in = sel == 0 ? w0 : sel == 1 ? w1 : sel == 2 ? w2 : w3;
  __hip_bfloat16* out = sel == 0 ? o0 : sel == 1 ? o1 : sel == 2 ? o2 : o3;
  const long i = (((long)(blockIdx.x & 127)) * 256 + threadIdx.x) * 8;
  float4 v0 = *(const float4*)(in + i);
  float4 v1 = *(const float4*)(in + i + 4);
  short8 o;
  __hip_bfloat16* ob = (__hip_bfloat16*)&o;
  ob[0] = __float2bfloat16(v0.x); ob[1] = __float2bfloat16(v0.y);
  ob[2] = __float2bfloat16(v0.z); ob[3] = __float2bfloat16(v0.w);
  ob[4] = __float2bfloat16(v1.x); ob[5] = __float2bfloat16(v1.y);
  ob[6] = __float2bfloat16(v1.z); ob[7] = __float2bfloat16(v1.w);
  *(short8*)(out + i) = o;
}

// X fp32 [B][4096][512] -> Xb bf16 + XTc bf16 [B*8][512 d][512 n]
__global__ __launch_bounds__(256)
void cvt_x_xt(const float* __restrict__ X,
              __hip_bfloat16* __restrict__ Xb,
              __hip_bfloat16* __restrict__ XT)
{
  __shared__ __hip_bfloat16 t[64][66];
  const int b  = blockIdx.z;
  const int n0 = blockIdx.y * 64;
  const int d0 = blockIdx.x * 64;
  const float* I = X + (size_t)b * 4096 * 512;
  __hip_bfloat16* XB = Xb + (size_t)b * 4096 * 512;
  __hip_bfloat16* XO = XT + ((size_t)b * 8 + (n0 >> 9)) * 512 * 512;
  const int nl0 = n0 & 511;
  const int tid = threadIdx.x;
#pragma unroll
  for (int it = 0; it < 4; ++it) {
    const int idx = it * 256 + tid;
    const int r   = idx >> 4;
    const int c4  = (idx & 15) * 4;
    float4 v = *(const float4*)&I[(size_t)(n0 + r) * 512 + d0 + c4];
    short4v o;
    __hip_bfloat16* ob = (__hip_bfloat16*)&o;
    ob[0] = __float2bfloat16(v.x); ob[1] = __float2bfloat16(v.y);
    ob[2] = __float2bfloat16(v.z); ob[3] = __float2bfloat16(v.w);
    t[r][c4]     = ob[0]; t[r][c4 + 1] = ob[1];
    t[r][c4 + 2] = ob[2]; t[r][c4 + 3] = ob[3];
    *(short4v*)&XB[(size_t)(n0 + r) * 512 + d0 + c4] = o;
  }
  __syncthreads();
#pragma unroll
  for (int it = 0; it < 4; ++it) {
    const int idx = it * 256 + tid;
    const int dr  = idx >> 4;
    const int n4  = (idx & 15) * 4;
    short4v o;
    __hip_bfloat16* ob = (__hip_bfloat16*)&o;
#pragma unroll
    for (int j = 0; j < 4; j++) ob[j] = t[n4 + j][dr];
    *(short4v*)&XO[(size_t)(d0 + dr) * 512 + nl0 + n4] = o;
  }
}

// W1n [32768 n][512 p] bf16 -> W1Tc [64 chunks][512 p][512 n-local]
__global__ __launch_bounds__(256)
void transpose_w1(const __hip_bfloat16* __restrict__ in,
                  __hip_bfloat16* __restrict__ out)
{
  __shared__ __hip_bfloat16 t[64][66];
  const int b  = blockIdx.z;
  const int n0 = blockIdx.y * 64;
  const int p0 = blockIdx.x * 64;
  const __hip_bfloat16* I = in + (size_t)b * 4096 * 512;
  __hip_bfloat16* O = out + ((size_t)b * 8 + (n0 >> 9)) * 512 * 512;
  const int nl0 = n0 & 511;
  const int tid = threadIdx.x;
#pragma unroll
  for (int it = 0; it < 2; ++it) {
    const int idx = it * 256 + tid;
    const int r   = idx >> 3;
    const int c8  = (idx & 7) * 8;
    short8 v = *(const short8*)&I[(size_t)(n0 + r) * 512 + p0 + c8];
#pragma unroll
    for (int j = 0; j < 8; j++) t[r][c8 + j] = ((const __hip_bfloat16*)&v)[j];
  }
  __syncthreads();
#pragma unroll
  for (int it = 0; it < 2; ++it) {
    const int idx = it * 256 + tid;
    const int dr  = idx >> 3;
    const int n8  = (idx & 7) * 8;
    short8 o;
#pragma unroll
    for (int j = 0; j < 8; j++) ((__hip_bfloat16*)&o)[j] = t[n8 + j][dr];
    *(short8*)&O[(size_t)(p0 + dr) * 512 + nl0 + n8] = o;
  }
}

// AT[b][i] = bf16(GELU(sum_q part[(b*4+q)][i])), q = 0..3
__global__ __launch_bounds__(256)
void reduce_gelu_bf16(const __hip_bfloat16* __restrict__ part,
                      __hip_bfloat16* __restrict__ AT) {
  const long o = ((long)blockIdx.x * 256 + threadIdx.x) * 8;
  const long b = o >> 18;
  const long i = o & 262143;
  float s[8] = {0.f, 0.f, 0.f, 0.f, 0.f, 0.f, 0.f, 0.f};
#pragma unroll
  for (int q = 0; q < 4; q++) {
    short8 v = *(const short8*)(part + (((b << 2) + q) << 18) + i);
#pragma unroll
    for (int j = 0; j < 8; j++) s[j] += __bfloat162float(((const __hip_bfloat16*)&v)[j]);
  }
  short8 o8;
#pragma unroll
  for (int j = 0; j < 8; j++)
    ((__hip_bfloat16*)&o8)[j] = __float2bfloat16(gelu_fast(s[j]));
  *(short8*)(AT + o) = o8;
}

extern "C" void kernel_launch(void* const* d_in, const int* in_sizes, int n_in,
                              void* d_out, int out_size, void* d_ws, size_t ws_size,
                              hipStream_t stream) {
  const float* X   = (const float*)d_in[0];
  const float* W1a = (const float*)d_in[1];
  const float* b1a = (const float*)d_in[2];
  const float* W1b = (const float*)d_in[3];
  const float* b1b = (const float*)d_in[4];
  const float* W2a = (const float*)d_in[5];
  const float* b2a = (const float*)d_in[6];
  const float* W2b = (const float*)d_in[7];
  const float* b2b = (const float*)d_in[8];
  float* Y = (float*)d_out;

  char* ws = (char*)d_ws;
  const size_t SZ = 33554432;  // 32768*512*2 B
  __hip_bfloat16* R0 = (__hip_bfloat16*)(ws);
  __hip_bfloat16* R1 = (__hip_bfloat16*)(ws + SZ);
  __hip_bfloat16* R2 = (__hip_bfloat16*)(ws + 2 * SZ);
  __hip_bfloat16* R3 = (__hip_bfloat16*)(ws + 3 * SZ);
  __hip_bfloat16* AT = (__hip_bfloat16*)(ws + 4 * SZ);              // 4MB
  __hip_bfloat16* Wb = (__hip_bfloat16*)(ws + 4 * SZ + 4194304);    // 2MB
  __hip_bfloat16* R4 = (__hip_bfloat16*)(ws + 4 * SZ + 6291456);    // 32MB (optional)
  const bool big_ws = ws_size >= (4 * SZ + 6291456 + SZ);           // 174MB
  __hip_bfloat16* W1ab = Wb;
  __hip_bfloat16* W1bb = Wb + 262144;
  __hip_bfloat16* W2ab = Wb + 2 * 262144;
  __hip_bfloat16* W2bb = Wb + 3 * 262144;

  dim3 blk(256), blk512(512);

  // 0) conversions; X also emits chunked XTc
  cvt_w4<<<512, blk, 0, stream>>>(W1a, W1b, W2a, W2b, W1ab, W1bb, W2ab, W2bb);
  __hip_bfloat16* Xb  = R0;
  __hip_bfloat16* XTc = R3;
  cvt_x_xt<<<dim3(8, 64, 8), blk, 0, stream>>>(X, Xb, XTc);

  // 1) H1 and H2 in one dispatch (shared A = Xb); GELU in one 64MB pass
  __hip_bfloat16* H1 = R1;
  __hip_bfloat16* H2 = R2;
  g128_h12<<<dim3(4, 256, 2), blk512, 0, stream>>>(Xb, W1ab, W2ab, b1a, b2a, H1, H2);
  gelu_inplace<<<16384, blk, 0, stream>>>(H1, 33554432L);

  if (big_ws) {
    // 2) W1n and W2m in one dispatch (Xb dead -> W1n in R0; W2m in R4)
    __hip_bfloat16* W1n = R0;
    __hip_bfloat16* W2m = R4;
    g128_w12<<<dim3(4, 256, 2), blk512, 0, stream>>>(H1, H2, W1bb, W2bb, b1b, b2b, W1n, W2m);
    // 3) W1Tc = chunk-transpose(W1n) -> R1 (H1 dead)
    __hip_bfloat16* W1Tc = R1;
    transpose_w1<<<dim3(8, 64, 8), blk, 0, stream>>>(W1n, W1Tc);
    // 4) P partials -> R2 (H2 dead)
    __hip_bfloat16* part = R2;
    g128_p<<<dim3(4, 4, 32), blk512, 0, stream>>>(XTc, W1Tc, part);
    // 5) AT = GELU(sum_q part)
    reduce_gelu_bf16<<<1024, blk, 0, stream>>>(part, AT);
    // 6) Y = W2m @ AT^T per batch -> fp32
    g128_y<<<dim3(4, 32, 8), blk512, 0, stream>>>(W2m, AT, Y);
  } else {
    // Fallback: R22-style sequence
    __hip_bfloat16* W1n = R0;
    g128_w1<<<dim3(4, 256, 1), blk512, 0, stream>>>(H1, W1bb, b1b, W1n);
    __hip_bfloat16* W1Tc = R1;
    transpose_w1<<<dim3(8, 64, 8), blk, 0, stream>>>(W1n, W1Tc);
    __hip_bfloat16* part = R0;
    g128_p<<<dim3(4, 4, 32), blk512, 0, stream>>>(XTc, W1Tc, part);
    reduce_gelu_bf16<<<1024, blk, 0, stream>>>(part, AT);
    __hip_bfloat16* W2m = R3;
    g128_w2<<<dim3(4, 256, 1), blk512, 0, stream>>>(H2, W2bb, b2b, W2m);
    g128_y<<<dim3(4, 32, 8), blk512, 0, stream>>>(W2m, AT, Y);
  }
}

// Round 26
// 186.515 us; speedup vs baseline: 1.6586x; 1.6586x over previous
//
#include <hip/hip_runtime.h>
#include <hip/hip_bf16.h>

typedef __attribute__((ext_vector_type(8))) short short8;
typedef __attribute__((ext_vector_type(4))) short short4v;
typedef __attribute__((ext_vector_type(4))) float floatx4;

__device__ __forceinline__ void gload_lds16(const void* g, void* l) {
  __builtin_amdgcn_global_load_lds(
      (const __attribute__((address_space(1))) void*)g,
      (__attribute__((address_space(3))) void*)l, 16, 0, 0);
}

// tanh-approx GELU via sigmoid; branch-free (v_exp + v_rcp)
__device__ __forceinline__ float gelu_fast(float x) {
  float z = 1.5957691216f * (x + 0.044715f * x * x * x);
  float e = __expf(-z);
  return x * __builtin_amdgcn_rcpf(1.0f + e);
}

#define FENCE() asm volatile("" ::: "memory")

// ========= 128x128x(K=512) BK=64 NT GEMM core — 512 thr / 8 waves =========
// 8 waves (2x4), per-wave out 64x32, dbuf LDS 64KB -> 2 blk/CU -> 16 waves/CU.
// T2 swizzle; STAGE-before-compute; one vmcnt(0)+barrier per K-step.
// B MUST be LDS-staged (R25: streaming B from L2 = 2x regression).
// GELU-in-epilogue BANNED (R14: +32us pathology). Swizzle computed by caller.
template<bool HASBIAS, bool OUT_F32>
__device__ __forceinline__
void gemm128_core(const __hip_bfloat16* __restrict__ A,
                  const __hip_bfloat16* __restrict__ B,
                  const float* __restrict__ bias,
                  void* __restrict__ C,
                  int bx, int by)
{
  __shared__ __align__(16) __hip_bfloat16 SB[2][2 * 128 * 64];  // 64KB

  const int tid  = threadIdx.x;
  const int lane = tid & 63;
  const int wid  = tid >> 6;   // 0..7
  const int wr   = wid >> 2;   // 0..1 (row half: 64 rows)
  const int wc   = wid & 3;    // 0..3 (col quarter: 32 cols)
  const int brow = by * 128;
  const int bcol = bx * 128;

  floatx4 acc[4][2];
#pragma unroll
  for (int i = 0; i < 4; i++)
#pragma unroll
    for (int j = 0; j < 2; j++) acc[i][j] = (floatx4){0.f, 0.f, 0.f, 0.f};

  // staging: 2 rounds x 64 rows; row = r*64 + (tid>>3); slot tid&7
  const int srow  = tid >> 3;                       // 0..63
  const int skoff = (((tid & 7) ^ (srow & 7))) * 8;

  auto STAGE = [&](int buf, int kt) {
    const int k0 = kt * 64;
#pragma unroll
    for (int r = 0; r < 2; ++r) {
      gload_lds16(A + (size_t)(brow + r * 64 + srow) * 512 + k0 + skoff,
                  (void*)(&SB[buf][0] + r * 4096 + tid * 8));
      gload_lds16(B + (size_t)(bcol + r * 64 + srow) * 512 + k0 + skoff,
                  (void*)(&SB[buf][8192] + r * 4096 + tid * 8));
    }
  };

  const int rs0 = (((lane >> 4)) ^ (lane & 7)) * 8;
  const int rs1 = ((4 + (lane >> 4)) ^ (lane & 7)) * 8;

  STAGE(0, 0);
  asm volatile("s_waitcnt vmcnt(0)" ::: "memory");
  __builtin_amdgcn_s_barrier();
  FENCE();

  for (int kt = 0; kt < 8; ++kt) {
    const int cur = kt & 1;
    if (kt < 7) STAGE(cur ^ 1, kt + 1);   // next-tile loads fly under compute
    const __hip_bfloat16* As = &SB[cur][0];
    const __hip_bfloat16* Bs = &SB[cur][8192];
    __builtin_amdgcn_s_setprio(1);
#pragma unroll
    for (int kk = 0; kk < 2; ++kk) {
      const int rs = kk ? rs1 : rs0;
      short8 a[4], b[2];
#pragma unroll
      for (int i = 0; i < 4; i++)
        a[i] = *(const short8*)(As + (wr * 64 + i * 16 + (lane & 15)) * 64 + rs);
#pragma unroll
      for (int j = 0; j < 2; j++)
        b[j] = *(const short8*)(Bs + (wc * 32 + j * 16 + (lane & 15)) * 64 + rs);
#pragma unroll
      for (int i = 0; i < 4; i++)
#pragma unroll
        for (int j = 0; j < 2; j++)
          acc[i][j] = __builtin_amdgcn_mfma_f32_16x16x32_bf16(a[i], b[j], acc[i][j], 0, 0, 0);
    }
    __builtin_amdgcn_s_setprio(0);

    if (kt < 7) {
      asm volatile("s_waitcnt vmcnt(0)" ::: "memory");
      __builtin_amdgcn_s_barrier();
      FENCE();
    }
  }

  // epilogue: C/D layout col=lane&15, row=(lane>>4)*4+reg
#pragma unroll
  for (int i = 0; i < 4; i++) {
    const int row0 = brow + wr * 64 + i * 16 + (lane >> 4) * 4;
#pragma unroll
    for (int j = 0; j < 2; j++) {
      const int col = bcol + wc * 32 + j * 16 + (lane & 15);
      const float bv = HASBIAS ? bias[col] : 0.f;
#pragma unroll
      for (int r = 0; r < 4; r++) {
        float v = acc[i][j][r] + bv;
        if (OUT_F32)
          ((float*)C)[(size_t)(row0 + r) * 512 + col] = v;
        else
          ((__hip_bfloat16*)C)[(size_t)(row0 + r) * 512 + col] = __float2bfloat16(v);
      }
    }
  }
}

// chunked-XCD swizzle helper: flat id -> (bx, by, bz); total must be /8
__device__ __forceinline__ void swz_chunked(int gx, int gy, int total,
                                            int& bx, int& by, int& bz) {
  const int f = blockIdx.x + gx * (blockIdx.y + gy * blockIdx.z);
  const int l = (f & 7) * (total >> 3) + (f >> 3);
  bx = l % gx;
  const int rr = l / gx;
  by = rr % gy;
  bz = rr / gy;
}

// ---- named instantiations ----
// h12: grid (4,256,2) — bz selects {W1a,b1a,H1} vs {W2a,b2a,H2}; shared A=Xb.
__global__ __launch_bounds__(512, 2)
void g128_h12(const __hip_bfloat16* Xb,
              const __hip_bfloat16* W1a, const __hip_bfloat16* W2a,
              const float* b1a, const float* b2a,
              __hip_bfloat16* H1, __hip_bfloat16* H2) {
  int bx, by, bz;
  swz_chunked(4, 256, 2048, bx, by, bz);
  const __hip_bfloat16* B = bz ? W2a : W1a;
  const float* bias       = bz ? b2a : b1a;
  __hip_bfloat16* C       = bz ? H2 : H1;
  gemm128_core<true, false>(Xb, B, bias, C, bx, by);
}
// w12: grid (4,256,2) — bz selects {H1,W1b,b1b,W1n} vs {H2,W2b,b2b,W2m}.
__global__ __launch_bounds__(512, 2)
void g128_w12(const __hip_bfloat16* H1, const __hip_bfloat16* H2,
              const __hip_bfloat16* W1b, const __hip_bfloat16* W2b,
              const float* b1b, const float* b2b,
              __hip_bfloat16* W1n, __hip_bfloat16* W2m) {
  int bx, by, bz;
  swz_chunked(4, 256, 2048, bx, by, bz);
  const __hip_bfloat16* A = bz ? H2 : H1;
  const __hip_bfloat16* B = bz ? W2b : W1b;
  const float* bias       = bz ? b2b : b1b;
  __hip_bfloat16* C       = bz ? W2m : W1n;
  gemm128_core<true, false>(A, B, bias, C, bx, by);
}
__global__ __launch_bounds__(512, 2)
void g128_w1(const __hip_bfloat16* A, const __hip_bfloat16* B, const float* bias,
             __hip_bfloat16* C) {
  int bx, by, bz;
  swz_chunked(4, 256, 1024, bx, by, bz);
  gemm128_core<true, false>(A, B, bias, C, bx, by);
}
__global__ __launch_bounds__(512, 2)
void g128_w2(const __hip_bfloat16* A, const __hip_bfloat16* B, const float* bias,
             __hip_bfloat16* C) {
  int bx, by, bz;
  swz_chunked(4, 256, 1024, bx, by, bz);
  gemm128_core<true, false>(A, B, bias, C, bx, by);
}
// y: grid (4,32,8) — batch bz; fp32 out
__global__ __launch_bounds__(512, 2)
void g128_y(const __hip_bfloat16* A, const __hip_bfloat16* B, float* C) {
  int bx, by, bz;
  swz_chunked(4, 32, 1024, bx, by, bz);
  gemm128_core<false, true>(A + (size_t)bz * 4096 * 512,
                            B + (size_t)bz * 262144, nullptr,
                            C + (size_t)bz * 4096 * 512, bx, by);
}

// ====== P kernel: 2 kc-chunks accumulated per block (K=1024, 16 steps) ======
// grid (4,4,32) = 512 blocks (2 blk/CU); 512 thr / 8 waves each.
__global__ __launch_bounds__(512, 2)
void g128_p(const __hip_bfloat16* __restrict__ Ag,
            const __hip_bfloat16* __restrict__ Bg,
            __hip_bfloat16* __restrict__ Cg)
{
  const int f = blockIdx.x + 4 * (blockIdx.y + 4 * blockIdx.z);
  const int xcd = f & 7, s = f >> 3;     // s: 0..63
  const int zq = xcd + 8 * (s >> 4);     // 0..31
  const int t  = s & 15;
  const int by = t >> 2;
  const int bx = t & 3;

  const __hip_bfloat16* A = Ag + (size_t)zq * 2 * 262144;
  const __hip_bfloat16* B = Bg + (size_t)zq * 2 * 262144;
  __hip_bfloat16*       C = Cg + (size_t)zq * 262144;

  __shared__ __align__(16) __hip_bfloat16 SB[2][2 * 128 * 64];  // 64KB

  const int tid  = threadIdx.x;
  const int lane = tid & 63;
  const int wid  = tid >> 6;   // 0..7
  const int wr   = wid >> 2;   // 0..1
  const int wc   = wid & 3;    // 0..3
  const int brow = by * 128;
  const int bcol = bx * 128;

  floatx4 acc[4][2];
#pragma unroll
  for (int i = 0; i < 4; i++)
#pragma unroll
    for (int j = 0; j < 2; j++) acc[i][j] = (floatx4){0.f, 0.f, 0.f, 0.f};

  const int srow  = tid >> 3;                       // 0..63
  const int skoff = (((tid & 7) ^ (srow & 7))) * 8;

  auto STAGE = [&](int buf, int kt) {
    const size_t cb = (size_t)(kt >> 3) * 262144;   // chunk base
    const int k0 = (kt & 7) * 64;
#pragma unroll
    for (int r = 0; r < 2; ++r) {
      gload_lds16(A + cb + (size_t)(brow + r * 64 + srow) * 512 + k0 + skoff,
                  (void*)(&SB[buf][0] + r * 4096 + tid * 8));
      gload_lds16(B + cb + (size_t)(bcol + r * 64 + srow) * 512 + k0 + skoff,
                  (void*)(&SB[buf][8192] + r * 4096 + tid * 8));
    }
  };

  const int rs0 = (((lane >> 4)) ^ (lane & 7)) * 8;
  const int rs1 = ((4 + (lane >> 4)) ^ (lane & 7)) * 8;

  STAGE(0, 0);
  asm volatile("s_waitcnt vmcnt(0)" ::: "memory");
  __builtin_amdgcn_s_barrier();
  FENCE();

  for (int kt = 0; kt < 16; ++kt) {
    const int cur = kt & 1;
    if (kt < 15) STAGE(cur ^ 1, kt + 1);
    const __hip_bfloat16* As = &SB[cur][0];
    const __hip_bfloat16* Bs = &SB[cur][8192];
    __builtin_amdgcn_s_setprio(1);
#pragma unroll
    for (int kk = 0; kk < 2; ++kk) {
      const int rs = kk ? rs1 : rs0;
      short8 a[4], b[2];
#pragma unroll
      for (int i = 0; i < 4; i++)
        a[i] = *(const short8*)(As + (wr * 64 + i * 16 + (lane & 15)) * 64 + rs);
#pragma unroll
      for (int j = 0; j < 2; j++)
        b[j] = *(const short8*)(Bs + (wc * 32 + j * 16 + (lane & 15)) * 64 + rs);
#pragma unroll
      for (int i = 0; i < 4; i++)
#pragma unroll
        for (int j = 0; j < 2; j++)
          acc[i][j] = __builtin_amdgcn_mfma_f32_16x16x32_bf16(a[i], b[j], acc[i][j], 0, 0, 0);
    }
    __builtin_amdgcn_s_setprio(0);

    if (kt < 15) {
      asm volatile("s_waitcnt vmcnt(0)" ::: "memory");
      __builtin_amdgcn_s_barrier();
      FENCE();
    }
  }

#pragma unroll
  for (int i = 0; i < 4; i++) {
    const int row0 = brow + wr * 64 + i * 16 + (lane >> 4) * 4;
#pragma unroll
    for (int j = 0; j < 2; j++) {
      const int col = bcol + wc * 32 + j * 16 + (lane & 15);
#pragma unroll
      for (int r = 0; r < 4; r++)
        C[(size_t)(row0 + r) * 512 + col] = __float2bfloat16(acc[i][j][r]);
    }
  }
}

// in-place GELU over bf16 buffer, 8 elems/thread
__global__ __launch_bounds__(256)
void gelu_inplace(__hip_bfloat16* __restrict__ H, long n) {
  long i = ((long)blockIdx.x * 256 + threadIdx.x) * 8;
  if (i >= n) return;
  short8 v = *(const short8*)(H + i);
  short8 o;
#pragma unroll
  for (int j = 0; j < 8; j++) {
    float x = __bfloat162float(((const __hip_bfloat16*)&v)[j]);
    ((__hip_bfloat16*)&o)[j] = __float2bfloat16(gelu_fast(x));
  }
  *(short8*)(H + i) = o;
}

// fused fp32->bf16 for the four 512x512 weights (one launch)
__global__ __launch_bounds__(256)
void cvt_w4(const float* __restrict__ w0, const float* __restrict__ w1,
            const float* __restrict__ w2, const float* __restrict__ w3,
            __hip_bfloat16* __restrict__ o0, __hip_bfloat16* __restrict__ o1,
            __hip_bfloat16* __restrict__ o2, __hip_bfloat16* __restrict__ o3) {
  const int sel = blockIdx.x >> 7;           // 128 blocks per weight
  const float* in = sel == 0 ? w0 : sel == 1 ? w1 : sel == 2 ? w2 : w3;
  __hip_bfloat16* out = sel == 0 ? o0 : sel == 1 ? o1 : sel == 2 ? o2 : o3;
  const long i = (((long)(blockIdx.x & 127)) * 256 + threadIdx.x) * 8;
  float4 v0 = *(const float4*)(in + i);
  float4 v1 = *(const float4*)(in + i + 4);
  short8 o;
  __hip_bfloat16* ob = (__hip_bfloat16*)&o;
  ob[0] = __float2bfloat16(v0.x); ob[1] = __float2bfloat16(v0.y);
  ob[2] = __float2bfloat16(v0.z); ob[3] = __float2bfloat16(v0.w);
  ob[4] = __float2bfloat16(v1.x); ob[5] = __float2bfloat16(v1.y);
  ob[6] = __float2bfloat16(v1.z); ob[7] = __float2bfloat16(v1.w);
  *(short8*)(out + i) = o;
}

// X fp32 [B][4096][512] -> Xb bf16 + XTc bf16 [B*8][512 d][512 n]
__global__ __launch_bounds__(256)
void cvt_x_xt(const float* __restrict__ X,
              __hip_bfloat16* __restrict__ Xb,
              __hip_bfloat16* __restrict__ XT)
{
  __shared__ __hip_bfloat16 t[64][66];
  const int b  = blockIdx.z;
  const int n0 = blockIdx.y * 64;
  const int d0 = blockIdx.x * 64;
  const float* I = X + (size_t)b * 4096 * 512;
  __hip_bfloat16* XB = Xb + (size_t)b * 4096 * 512;
  __hip_bfloat16* XO = XT + ((size_t)b * 8 + (n0 >> 9)) * 512 * 512;
  const int nl0 = n0 & 511;
  const int tid = threadIdx.x;
#pragma unroll
  for (int it = 0; it < 4; ++it) {
    const int idx = it * 256 + tid;
    const int r   = idx >> 4;
    const int c4  = (idx & 15) * 4;
    float4 v = *(const float4*)&I[(size_t)(n0 + r) * 512 + d0 + c4];
    short4v o;
    __hip_bfloat16* ob = (__hip_bfloat16*)&o;
    ob[0] = __float2bfloat16(v.x); ob[1] = __float2bfloat16(v.y);
    ob[2] = __float2bfloat16(v.z); ob[3] = __float2bfloat16(v.w);
    t[r][c4]     = ob[0]; t[r][c4 + 1] = ob[1];
    t[r][c4 + 2] = ob[2]; t[r][c4 + 3] = ob[3];
    *(short4v*)&XB[(size_t)(n0 + r) * 512 + d0 + c4] = o;
  }
  __syncthreads();
#pragma unroll
  for (int it = 0; it < 4; ++it) {
    const int idx = it * 256 + tid;
    const int dr  = idx >> 4;
    const int n4  = (idx & 15) * 4;
    short4v o;
    __hip_bfloat16* ob = (__hip_bfloat16*)&o;
#pragma unroll
    for (int j = 0; j < 4; j++) ob[j] = t[n4 + j][dr];
    *(short4v*)&XO[(size_t)(d0 + dr) * 512 + nl0 + n4] = o;
  }
}

// W1n [32768 n][512 p] bf16 -> W1Tc [64 chunks][512 p][512 n-local]
__global__ __launch_bounds__(256)
void transpose_w1(const __hip_bfloat16* __restrict__ in,
                  __hip_bfloat16* __restrict__ out)
{
  __shared__ __hip_bfloat16 t[64][66];
  const int b  = blockIdx.z;
  const int n0 = blockIdx.y * 64;
  const int p0 = blockIdx.x * 64;
  const __hip_bfloat16* I = in + (size_t)b * 4096 * 512;
  __hip_bfloat16* O = out + ((size_t)b * 8 + (n0 >> 9)) * 512 * 512;
  const int nl0 = n0 & 511;
  const int tid = threadIdx.x;
#pragma unroll
  for (int it = 0; it < 2; ++it) {
    const int idx = it * 256 + tid;
    const int r   = idx >> 3;
    const int c8  = (idx & 7) * 8;
    short8 v = *(const short8*)&I[(size_t)(n0 + r) * 512 + p0 + c8];
#pragma unroll
    for (int j = 0; j < 8; j++) t[r][c8 + j] = ((const __hip_bfloat16*)&v)[j];
  }
  __syncthreads();
#pragma unroll
  for (int it = 0; it < 2; ++it) {
    const int idx = it * 256 + tid;
    const int dr  = idx >> 3;
    const int n8  = (idx & 7) * 8;
    short8 o;
#pragma unroll
    for (int j = 0; j < 8; j++) ((__hip_bfloat16*)&o)[j] = t[n8 + j][dr];
    *(short8*)&O[(size_t)(p0 + dr) * 512 + nl0 + n8] = o;
  }
}

// AT[b][i] = bf16(GELU(sum_q part[(b*4+q)][i])), q = 0..3
__global__ __launch_bounds__(256)
void reduce_gelu_bf16(const __hip_bfloat16* __restrict__ part,
                      __hip_bfloat16* __restrict__ AT) {
  const long o = ((long)blockIdx.x * 256 + threadIdx.x) * 8;
  const long b = o >> 18;
  const long i = o & 262143;
  float s[8] = {0.f, 0.f, 0.f, 0.f, 0.f, 0.f, 0.f, 0.f};
#pragma unroll
  for (int q = 0; q < 4; q++) {
    short8 v = *(const short8*)(part + (((b << 2) + q) << 18) + i);
#pragma unroll
    for (int j = 0; j < 8; j++) s[j] += __bfloat162float(((const __hip_bfloat16*)&v)[j]);
  }
  short8 o8;
#pragma unroll
  for (int j = 0; j < 8; j++)
    ((__hip_bfloat16*)&o8)[j] = __float2bfloat16(gelu_fast(s[j]));
  *(short8*)(AT + o) = o8;
}

extern "C" void kernel_launch(void* const* d_in, const int* in_sizes, int n_in,
                              void* d_out, int out_size, void* d_ws, size_t ws_size,
                              hipStream_t stream) {
  const float* X   = (const float*)d_in[0];
  const float* W1a = (const float*)d_in[1];
  const float* b1a = (const float*)d_in[2];
  const float* W1b = (const float*)d_in[3];
  const float* b1b = (const float*)d_in[4];
  const float* W2a = (const float*)d_in[5];
  const float* b2a = (const float*)d_in[6];
  const float* W2b = (const float*)d_in[7];
  const float* b2b = (const float*)d_in[8];
  float* Y = (float*)d_out;

  char* ws = (char*)d_ws;
  const size_t SZ = 33554432;  // 32768*512*2 B
  __hip_bfloat16* R0 = (__hip_bfloat16*)(ws);
  __hip_bfloat16* R1 = (__hip_bfloat16*)(ws + SZ);
  __hip_bfloat16* R2 = (__hip_bfloat16*)(ws + 2 * SZ);
  __hip_bfloat16* R3 = (__hip_bfloat16*)(ws + 3 * SZ);
  __hip_bfloat16* AT = (__hip_bfloat16*)(ws + 4 * SZ);              // 4MB
  __hip_bfloat16* Wb = (__hip_bfloat16*)(ws + 4 * SZ + 4194304);    // 2MB
  __hip_bfloat16* R4 = (__hip_bfloat16*)(ws + 4 * SZ + 6291456);    // 32MB (optional)
  const bool big_ws = ws_size >= (4 * SZ + 6291456 + SZ);           // 174MB
  __hip_bfloat16* W1ab = Wb;
  __hip_bfloat16* W1bb = Wb + 262144;
  __hip_bfloat16* W2ab = Wb + 2 * 262144;
  __hip_bfloat16* W2bb = Wb + 3 * 262144;

  dim3 blk(256), blk512(512);

  // 0) conversions; X also emits chunked XTc
  cvt_w4<<<512, blk, 0, stream>>>(W1a, W1b, W2a, W2b, W1ab, W1bb, W2ab, W2bb);
  __hip_bfloat16* Xb  = R0;
  __hip_bfloat16* XTc = R3;
  cvt_x_xt<<<dim3(8, 64, 8), blk, 0, stream>>>(X, Xb, XTc);

  // 1) H1 and H2 in one dispatch (shared A = Xb); GELU in one 64MB pass
  __hip_bfloat16* H1 = R1;
  __hip_bfloat16* H2 = R2;
  g128_h12<<<dim3(4, 256, 2), blk512, 0, stream>>>(Xb, W1ab, W2ab, b1a, b2a, H1, H2);
  gelu_inplace<<<16384, blk, 0, stream>>>(H1, 33554432L);

  if (big_ws) {
    // 2) W1n and W2m in one dispatch (Xb dead -> W1n in R0; W2m in R4)
    __hip_bfloat16* W1n = R0;
    __hip_bfloat16* W2m = R4;
    g128_w12<<<dim3(4, 256, 2), blk512, 0, stream>>>(H1, H2, W1bb, W2bb, b1b, b2b, W1n, W2m);
    // 3) W1Tc = chunk-transpose(W1n) -> R1 (H1 dead)
    __hip_bfloat16* W1Tc = R1;
    transpose_w1<<<dim3(8, 64, 8), blk, 0, stream>>>(W1n, W1Tc);
    // 4) P partials -> R2 (H2 dead)
    __hip_bfloat16* part = R2;
    g128_p<<<dim3(4, 4, 32), blk512, 0, stream>>>(XTc, W1Tc, part);
    // 5) AT = GELU(sum_q part)
    reduce_gelu_bf16<<<1024, blk, 0, stream>>>(part, AT);
    // 6) Y = W2m @ AT^T per batch -> fp32
    g128_y<<<dim3(4, 32, 8), blk512, 0, stream>>>(W2m, AT, Y);
  } else {
    // Fallback: R22-style sequence with 512-thr kernels
    __hip_bfloat16* W1n = R0;
    g128_w1<<<dim3(4, 256, 1), blk512, 0, stream>>>(H1, W1bb, b1b, W1n);
    __hip_bfloat16* W1Tc = R1;
    transpose_w1<<<dim3(8, 64, 8), blk, 0, stream>>>(W1n, W1Tc);
    __hip_bfloat16* part = R0;
    g128_p<<<dim3(4, 4, 32), blk512, 0, stream>>>(XTc, W1Tc, part);
    reduce_gelu_bf16<<<1024, blk, 0, stream>>>(part, AT);
    __hip_bfloat16* W2m = R3;
    g128_w2<<<dim3(4, 256, 1), blk512, 0, stream>>>(H2, W2bb, b2b, W2m);
    g128_y<<<dim3(4, 32, 8), blk512, 0, stream>>>(W2m, AT, Y);
  }
}